// Round 2
// baseline (1067.508 us; speedup 1.0000x reference)
//
#include <hip/hip_runtime.h>
#include <hip/hip_bf16.h>

#define H 256
#define W 256
#define CIN 128
#define COUT 128
#define BATCH 8

typedef float f32x4 __attribute__((ext_vector_type(4)));
typedef short bf16x8 __attribute__((ext_vector_type(8)));
typedef unsigned int u32;

// ws layout: wprep (294912 B) | scale[128] f32 | dacc[128] f32
#define WPREP_UNITS (9 * 4 * 8 * 64)          // 18432 x 16B
#define SCALE_OFF_F (294912 / 4)
#define DACC_OFF_F  (295424 / 4)

static __device__ __forceinline__ unsigned short f2bf(float f) {
    unsigned int x = __float_as_uint(f);
    unsigned int r = (x + 0x7fffu + ((x >> 16) & 1u)) >> 16;
    return (unsigned short)r;
}

// ---------------------------------------------------------------------------
// prep_a: 1 block x 1024 thr. s = style@w_mod + b_mod + 1; global max-abs;
// write scale[c] = s[0][c]/max * he_std; zero demod accumulator.
// ---------------------------------------------------------------------------
__global__ __launch_bounds__(1024) void prep_a(
    const float* __restrict__ style, const float* __restrict__ w_mod,
    const float* __restrict__ b_mod, float* __restrict__ ws_f)
{
    __shared__ float sbuf[1024];
    const int t = threadIdx.x;
    const int b = t >> 7;
    const int c = t & 127;

    float acc = 0.f;
    const float4* st4 = (const float4*)(style + b * 512);
    for (int k4 = 0; k4 < 128; ++k4) {
        float4 s4 = st4[k4];
        int k = k4 * 4;
        acc += s4.x * w_mod[(k + 0) * CIN + c];
        acc += s4.y * w_mod[(k + 1) * CIN + c];
        acc += s4.z * w_mod[(k + 2) * CIN + c];
        acc += s4.w * w_mod[(k + 3) * CIN + c];
    }
    float sval = acc + b_mod[c] + 1.0f;

    sbuf[t] = fabsf(sval);
    __syncthreads();
    for (int off = 512; off > 0; off >>= 1) {
        if (t < off) sbuf[t] = fmaxf(sbuf[t], sbuf[t + off]);
        __syncthreads();
    }
    float invmax = 1.0f / sbuf[0];
    const float he_std = 1.0f / sqrtf(1152.0f);
    if (t < 128) ws_f[SCALE_OFF_F + t] = sval * invmax * he_std;   // b==0 rows
    if (t >= 128 && t < 256) ws_f[DACC_OFF_F + (t - 128)] = 0.f;
}

// ---------------------------------------------------------------------------
// prep_b: 9 blocks x 256 thr. Block kk: partial sum_k (kern*scale)^2 per cout,
// atomicAdd into dacc.
// ---------------------------------------------------------------------------
__global__ __launch_bounds__(256) void prep_b(
    const float* __restrict__ kern, float* __restrict__ ws_f)
{
    __shared__ float sbuf[256];
    const int kk = blockIdx.x;
    const int t = threadIdx.x;
    const int co = t & 127;
    const int half = t >> 7;
    float ss = 0.f;
    for (int j = 0; j < 64; ++j) {
        int ci = half * 64 + j;
        float wv = kern[(kk * 128 + ci) * 128 + co] * ws_f[SCALE_OFF_F + ci];
        ss += wv * wv;
    }
    sbuf[t] = ss;
    __syncthreads();
    if (t < 128) atomicAdd(&ws_f[DACC_OFF_F + t], sbuf[t] + sbuf[t + 128]);
}

// ---------------------------------------------------------------------------
// prep_c: 72 blocks x 256 thr. One MFMA B-frag 16B unit per thread:
// unit u = ((kk*4+kc)*8 + ntile)*64 + lane holds
// B[k = kc*32 + (lane>>4)*8 + j][n = ntile*16 + (lane&15)]
// ---------------------------------------------------------------------------
__global__ __launch_bounds__(256) void prep_c(
    const float* __restrict__ kern, const float* __restrict__ ws_f,
    unsigned short* __restrict__ wprep)
{
    const int u = blockIdx.x * 256 + threadIdx.x;
    int lane  = u & 63;
    int ntile = (u >> 6) & 7;
    int kc    = (u >> 9) & 3;
    int kk    = u >> 11;
    int co  = ntile * 16 + (lane & 15);
    int cib = kc * 32 + (lane >> 4) * 8;
    float dv = rsqrtf(ws_f[DACC_OFF_F + co] + 1e-8f);
    unsigned int packed[4];
    for (int jp = 0; jp < 4; ++jp) {
        int ci0 = cib + jp * 2;
        float w0 = kern[(kk * 128 + ci0)     * 128 + co] * ws_f[SCALE_OFF_F + ci0]     * dv;
        float w1 = kern[(kk * 128 + ci0 + 1) * 128 + co] * ws_f[SCALE_OFF_F + ci0 + 1] * dv;
        packed[jp] = (unsigned int)f2bf(w0) | ((unsigned int)f2bf(w1) << 16);
    }
    ((uint4*)wprep)[u] = make_uint4(packed[0], packed[1], packed[2], packed[3]);
}

// ---------------------------------------------------------------------------
// conv: no LDS, no barriers. Block = 128 px x 128 cout, 4 waves (2x2), each
// wave 64x64 via 4x4 mfma_f32_16x16x32_bf16. A-frags read straight from
// global fp32 (L1/L2-hot rows), truncate-packed to bf16 via v_perm; halo
// lanes masked to zero. B-frags from L2-resident pre-swizzled wprep.
// ---------------------------------------------------------------------------
__global__ __launch_bounds__(256, 3) void conv_kernel(
    const float* __restrict__ x, const unsigned short* __restrict__ wprep,
    const float* __restrict__ noise_strength, const float* __restrict__ bias,
    const float* __restrict__ noise, float* __restrict__ out)
{
    const int tid  = threadIdx.x;
    const int lane = tid & 63;
    const int wave = tid >> 6;
    const int wm = wave & 1;
    const int wn = wave >> 1;
    const int wt = blockIdx.x;   // 0..1
    const int h  = blockIdx.y;   // 0..255
    const int b  = blockIdx.z;   // 0..7
    const int wstart = wt * 128;

    f32x4 acc[4][4];
    const f32x4 zero = {0.f, 0.f, 0.f, 0.f};
    #pragma unroll
    for (int i = 0; i < 4; ++i)
        #pragma unroll
        for (int j = 0; j < 4; ++j) acc[i][j] = zero;

    // per-(kw,i): float-element offset within row, and OOB mask
    int aoff[3][4];
    u32 amask[3][4];
    #pragma unroll
    for (int kw = 0; kw < 3; ++kw)
        #pragma unroll
        for (int i = 0; i < 4; ++i) {
            int wImg = wstart + wm * 64 + i * 16 + (lane & 15) + kw - 1;
            amask[kw][i] = ((unsigned)wImg < (unsigned)W) ? 0xFFFFFFFFu : 0u;
            int wC = min(max(wImg, 0), W - 1);
            aoff[kw][i] = wC * CIN + (lane >> 4) * 8;
        }

    const bf16x8* __restrict__ wf = (const bf16x8*)wprep;
    const int bvoff = wn * 4 * 64 + lane;   // per-lane frag-unit offset

    for (int kh = 0; kh < 3; ++kh) {
        const int hImg = h + kh - 1;
        if ((unsigned)hImg >= (unsigned)H) continue;   // uniform: zero padding row
        const float* __restrict__ rowPtr = x + ((size_t)(b * H + hImg) * W) * CIN;
        #pragma unroll
        for (int kc = 0; kc < 4; ++kc) {
            #pragma unroll
            for (int kw = 0; kw < 3; ++kw) {
                const int kk = kh * 3 + kw;
                bf16x8 bfrag[4];
                const bf16x8* bp = wf + ((kk * 4 + kc) * 8) * 64 + bvoff;
                #pragma unroll
                for (int j = 0; j < 4; ++j) bfrag[j] = bp[j * 64];
                bf16x8 afrag[4];
                #pragma unroll
                for (int i = 0; i < 4; ++i) {
                    const float* pA = rowPtr + aoff[kw][i] + kc * 32;
                    f32x4 a0 = *(const f32x4*)pA;
                    f32x4 a1 = *(const f32x4*)(pA + 4);
                    u32 m = amask[kw][i];
                    union { u32 u[4]; bf16x8 v; } cv;
                    cv.u[0] = __builtin_amdgcn_perm(__float_as_uint(a0.y), __float_as_uint(a0.x), 0x07060302u) & m;
                    cv.u[1] = __builtin_amdgcn_perm(__float_as_uint(a0.w), __float_as_uint(a0.z), 0x07060302u) & m;
                    cv.u[2] = __builtin_amdgcn_perm(__float_as_uint(a1.y), __float_as_uint(a1.x), 0x07060302u) & m;
                    cv.u[3] = __builtin_amdgcn_perm(__float_as_uint(a1.w), __float_as_uint(a1.z), 0x07060302u) & m;
                    afrag[i] = cv.v;
                }
                #pragma unroll
                for (int i = 0; i < 4; ++i)
                    #pragma unroll
                    for (int j = 0; j < 4; ++j)
                        acc[i][j] = __builtin_amdgcn_mfma_f32_16x16x32_bf16(
                            afrag[i], bfrag[j], acc[i][j], 0, 0, 0);
            }
        }
    }

    // epilogue: noise + bias + lrelu(0.2)*sqrt(2)
    const float ns  = noise_strength[0] * 0.5f;
    const float RT2 = 1.41421356237309515f;
    const size_t pixBase = ((size_t)(b * H + h) * W) + wstart;
    #pragma unroll
    for (int i = 0; i < 4; ++i) {
        const int mbase = wm * 64 + i * 16 + ((lane >> 4) << 2);
        #pragma unroll
        for (int r = 0; r < 4; ++r) {
            const size_t pix = pixBase + (mbase + r);
            const float nz = noise[pix] * ns;
            #pragma unroll
            for (int j = 0; j < 4; ++j) {
                const int col = wn * 64 + j * 16 + (lane & 15);
                float v = acc[i][j][r] + nz + bias[col];
                v = (v >= 0.f ? v : 0.2f * v) * RT2;
                out[pix * COUT + col] = v;
            }
        }
    }
}

extern "C" void kernel_launch(void* const* d_in, const int* in_sizes, int n_in,
                              void* d_out, int out_size, void* d_ws, size_t ws_size,
                              hipStream_t stream) {
    const float* x              = (const float*)d_in[0];
    const float* style          = (const float*)d_in[1];
    const float* kern           = (const float*)d_in[2];
    const float* w_mod          = (const float*)d_in[3];
    const float* b_mod          = (const float*)d_in[4];
    const float* noise_strength = (const float*)d_in[5];
    const float* bias           = (const float*)d_in[6];
    const float* noise          = (const float*)d_in[7];
    float* out = (float*)d_out;
    unsigned short* wprep = (unsigned short*)d_ws;
    float* ws_f = (float*)d_ws;

    hipLaunchKernelGGL(prep_a, dim3(1), dim3(1024), 0, stream, style, w_mod, b_mod, ws_f);
    hipLaunchKernelGGL(prep_b, dim3(9), dim3(256), 0, stream, kern, ws_f);
    hipLaunchKernelGGL(prep_c, dim3(72), dim3(256), 0, stream, kern, ws_f, wprep);
    hipLaunchKernelGGL(conv_kernel, dim3(2, 256, 8), dim3(256), 0, stream,
                       x, wprep, noise_strength, bias, noise, out);
}